// Round 2
// baseline (665.587 us; speedup 1.0000x reference)
//
#include <hip/hip_runtime.h>
#include <stdint.h>
#include <math.h>

#define D_MODEL 1024
#define D_STATE 128
#define D_INNER 2048
#define DT_RANK 64
#define BATCH   2
#define SEQ     2048
#define TOKENS  (BATCH*SEQ)        // 4096
#define NPROJ   (DT_RANK + 2*D_STATE) // 320

typedef unsigned short u16;
typedef __attribute__((ext_vector_type(4))) float f32x4;
typedef __attribute__((ext_vector_type(8))) short s16x8;
typedef __attribute__((ext_vector_type(4))) unsigned short u16x4;

static __device__ __forceinline__ u16 f2bf(float f) {
  unsigned u = __builtin_bit_cast(unsigned, f);
  return (u16)((u + 0x7FFFu + ((u >> 16) & 1u)) >> 16);
}
static __device__ __forceinline__ float bf2f(u16 h) {
  return __builtin_bit_cast(float, ((unsigned)h) << 16);
}
static __device__ __forceinline__ float bf2f_lo(unsigned w) {
  return __builtin_bit_cast(float, w << 16);
}
static __device__ __forceinline__ float bf2f_hi(unsigned w) {
  return __builtin_bit_cast(float, w & 0xFFFF0000u);
}

static __device__ __forceinline__ void gload_lds16(const void* g, void* l) {
  __builtin_amdgcn_global_load_lds(
      (const __attribute__((address_space(1))) void*)g,
      (__attribute__((address_space(3))) void*)l, 16, 0, 0);
}

// ---------------- fp32 -> bf16 convert (vec4) ----------------
__global__ void k_cvt_bf16(const float* __restrict__ in, u16* __restrict__ out, int n4) {
  int i = blockIdx.x * blockDim.x + threadIdx.x;
  if (i >= n4) return;
  f32x4 v = ((const f32x4*)in)[i];
  u16x4 o;
  o.x = f2bf(v.x); o.y = f2bf(v.y); o.z = f2bf(v.z); o.w = f2bf(v.w);
  ((u16x4*)out)[i] = o;
}

// ---------------- bf16 GEMM: C = A @ B^T ----------------
// A: (M,K) bf16 row-major, B: (N,K) bf16 row-major.
// EPI: 0 = f32 store, 1 = bf16 store, 2 = softplus(acc + 2*bias[col]) f32 store
#define BM 128
#define BN 128
#define BK 64

template<int EPI>
__global__ __launch_bounds__(256) void k_gemm_bt(
    const u16* __restrict__ A, const u16* __restrict__ B,
    void* __restrict__ C, const float* __restrict__ bias,
    int M, int N, int K, int ldc)
{
  __shared__ __align__(16) u16 As[BM*BK];
  __shared__ __align__(16) u16 Bs[BN*BK];
  const int tid  = threadIdx.x;
  const int lane = tid & 63;
  const int wid  = tid >> 6;
  const int wr   = (wid >> 1) * 64;
  const int wc   = (wid & 1) * 64;
  const int bm   = blockIdx.x * BM;
  const int bn   = blockIdx.y * BN;
  const int lr   = lane & 15;        // row/col within 16x16 frag
  const int lk   = (lane >> 4) * 8;  // k offset within 32

  f32x4 acc[4][4] = {};

  for (int k0 = 0; k0 < K; k0 += BK) {
    // stage A and B tiles: 16KB each = 1024 chunks of 16B, 4 per thread
    #pragma unroll
    for (int i = 0; i < 4; ++i) {
      int c   = tid + i * 256;
      int row = c >> 3;
      int col = (c & 7) * 8;
      const u16* ga = A + (size_t)(bm + row) * K + (k0 + col);
      gload_lds16(ga, As + (size_t)c * 8);
      int brow = bn + row; brow = brow < N ? brow : N - 1; // clamp for N tail
      const u16* gb = B + (size_t)brow * K + (k0 + col);
      gload_lds16(gb, Bs + (size_t)c * 8);
    }
    __syncthreads();

    #pragma unroll
    for (int kk = 0; kk < BK; kk += 32) {
      s16x8 af[4], bf[4];
      #pragma unroll
      for (int m = 0; m < 4; ++m)
        af[m] = *(const s16x8*)(As + (size_t)(wr + m*16 + lr) * BK + kk + lk);
      #pragma unroll
      for (int n = 0; n < 4; ++n)
        bf[n] = *(const s16x8*)(Bs + (size_t)(wc + n*16 + lr) * BK + kk + lk);
      #pragma unroll
      for (int m = 0; m < 4; ++m)
        #pragma unroll
        for (int n = 0; n < 4; ++n)
          acc[m][n] = __builtin_amdgcn_mfma_f32_16x16x32_bf16(af[m], bf[n], acc[m][n], 0, 0, 0);
    }
    __syncthreads();
  }

  // epilogue: D row = (lane>>4)*4 + reg, col = lane&15  [m89-verified layout]
  const int orow0 = bm + wr + (lane >> 4) * 4;
  const int ocol0 = bn + wc + lr;
  #pragma unroll
  for (int m = 0; m < 4; ++m) {
    #pragma unroll
    for (int n = 0; n < 4; ++n) {
      int col = ocol0 + n * 16;
      if (col >= N) continue;
      #pragma unroll
      for (int r = 0; r < 4; ++r) {
        int row = orow0 + m * 16 + r;
        float v = acc[m][n][r];
        if (EPI == 2) {
          v = v + 2.0f * bias[col];
          v = (v > 20.0f) ? v : log1pf(__expf(v));
        }
        if (EPI == 1) ((u16*)C)[(size_t)row * ldc + col] = f2bf(v);
        else          ((float*)C)[(size_t)row * ldc + col] = v;
      }
    }
  }
}

// ---------------- depthwise causal conv (K=4) + SiLU ----------------
// xz: (TOKENS, 2*D_INNER) bf16; u: (TOKENS, D_INNER) bf16
__global__ __launch_bounds__(256) void k_conv_silu(
    const u16* __restrict__ xz, const float* __restrict__ cw,
    const float* __restrict__ cb, u16* __restrict__ u)
{
  int idx = blockIdx.x * 256 + threadIdx.x; // over TOKENS*D_INNER (exact)
  int d   = idx & (D_INNER - 1);
  int tok = idx >> 11;
  int t   = tok & (SEQ - 1);
  int b   = tok >> 11;
  f32x4 w = *(const f32x4*)(cw + (size_t)d * 4);
  float acc = cb[d];
  #pragma unroll
  for (int j = 0; j < 4; ++j) {
    int tt = t - 3 + j;
    if (tt >= 0)
      acc += bf2f(xz[(size_t)(b * SEQ + tt) * (2*D_INNER) + d]) * w[j];
  }
  float s = acc / (1.0f + __expf(-acc));
  u[(size_t)tok * D_INNER + d] = f2bf(s);
}

// ---------------- split x_dbl -> dtlo bf16, interleaved BC bf16 ----------------
// BC layout per token: 64 groups of [B(2n),B(2n+1),C(2n),C(2n+1)] (256 u16)
__global__ void k_split(const float* __restrict__ xdbl, u16* __restrict__ dtlo,
                        u16* __restrict__ BC)
{
  int idx = blockIdx.x * 256 + threadIdx.x;
  if (idx >= TOKENS * NPROJ) return;
  int row = idx / NPROJ;
  int c   = idx - row * NPROJ;
  u16 h = f2bf(xdbl[idx]);
  if (c < DT_RANK) {
    dtlo[(size_t)row * DT_RANK + c] = h;
  } else if (c < DT_RANK + D_STATE) {
    int n = c - DT_RANK;
    BC[(size_t)row * 256 + (n >> 1) * 4 + (n & 1)] = h;
  } else {
    int n = c - DT_RANK - D_STATE;
    BC[(size_t)row * 256 + (n >> 1) * 4 + 2 + (n & 1)] = h;
  }
}

// ---------------- DPP wave64 sum (result in lane 63) ----------------
template<int CTRL>
static __device__ __forceinline__ float dpp_add(float x) {
  int t = __builtin_amdgcn_update_dpp(0, __builtin_bit_cast(int, x), CTRL, 0xf, 0xf, true);
  return x + __builtin_bit_cast(float, t);
}
static __device__ __forceinline__ float wave_sum_to63(float x) {
  x = dpp_add<0x111>(x); // row_shr:1
  x = dpp_add<0x112>(x); // row_shr:2
  x = dpp_add<0x114>(x); // row_shr:4
  x = dpp_add<0x118>(x); // row_shr:8
  x = dpp_add<0x142>(x); // row_bcast:15
  x = dpp_add<0x143>(x); // row_bcast:31
  return x;
}
static __device__ __forceinline__ float bcast_lane(float v, int l) {
  return __builtin_bit_cast(float, __builtin_amdgcn_readlane(__builtin_bit_cast(int, v), l));
}

// ---------------- selective scan: 1 wave per (b,d), 2 states/lane ----------------
// ysT layout: [d][b][t]  (coalesced 128B stores per 64-step chunk)
__global__ __launch_bounds__(256) void k_scan(
    const float* __restrict__ dt, const u16* __restrict__ ub,
    const u16* __restrict__ BC, const float* __restrict__ A_log,
    u16* __restrict__ ysT)
{
  const int lane = threadIdx.x & 63;
  const int gw   = blockIdx.x * 4 + (threadIdx.x >> 6);
  const int b    = gw >> 11;
  const int d    = gw & (D_INNER - 1);

  float2 al = *(const float2*)(A_log + (size_t)d * D_STATE + 2 * lane);
  const float A0 = -__expf(al.x);   // == -(2*lane+1); A1 = A0 - 1 handled via r-trick
  float h0 = 0.f, h1 = 0.f;

  const float* dt_col = dt + (size_t)b * SEQ * D_INNER + d;
  const u16*   u_col  = ub + (size_t)b * SEQ * D_INNER + d;
  const u16*   BCb    = BC + (size_t)b * SEQ * 256 + 4 * lane;
  u16* yo = ysT + ((size_t)d * BATCH + b) * SEQ;

  for (int t0 = 0; t0 < SEQ; t0 += 64) {
    float dtl  = dt_col[(size_t)(t0 + lane) * D_INNER];
    float ul   = bf2f(u_col[(size_t)(t0 + lane) * D_INNER]);
    float rl   = __expf(-dtl);      // exp(-dt) for this lane's step
    float dtul = dtl * ul;
    float yout = 0.f;
    #pragma unroll 8
    for (int tt = 0; tt < 64; ++tt) {
      float dt_t  = bcast_lane(dtl,  tt);
      float r_t   = bcast_lane(rl,   tt);
      float dtu_t = bcast_lane(dtul, tt);
      uint2 w = *(const uint2*)(BCb + (size_t)(t0 + tt) * 256);
      float B0 = bf2f_lo(w.x), B1 = bf2f_hi(w.x);
      float C0 = bf2f_lo(w.y), C1 = bf2f_hi(w.y);
      float dA0 = __expf(dt_t * A0);   // exp(dt * A[2l])
      float dA1 = dA0 * r_t;           // exp(dt * A[2l+1]) (A spacing = -1)
      h0 = fmaf(dA0, h0, dtu_t * B0);
      h1 = fmaf(dA1, h1, dtu_t * B1);
      float yp = fmaf(h1, C1, h0 * C0);
      yp = wave_sum_to63(yp);
      float ytot = bcast_lane(yp, 63);
      yout = (lane == tt) ? ytot : yout;
    }
    yo[t0 + lane] = f2bf(yout);
  }
}

// ---------------- gate: yg = (ysT^T + u*Dp) * silu(z), tiled transpose ----------------
__global__ __launch_bounds__(256) void k_gate(
    const u16* __restrict__ ysT, const u16* __restrict__ ub,
    const u16* __restrict__ xz, const float* __restrict__ Dp,
    u16* __restrict__ yg)
{
  __shared__ u16 tile[64][68];
  const int tid  = threadIdx.x;
  const int c    = tid & 63;
  const int rb   = tid >> 6;
  const int tok0 = blockIdx.x * 64;
  const int d0   = blockIdx.y * 64;
  const int bb   = tok0 >> 11;
  const int t0   = tok0 & (SEQ - 1);

  #pragma unroll
  for (int j = 0; j < 16; ++j) {
    int dl = rb + j * 4;
    tile[dl][c] = ysT[((size_t)(d0 + dl) * BATCH + bb) * SEQ + t0 + c];
  }
  __syncthreads();
  #pragma unroll
  for (int j = 0; j < 16; ++j) {
    int tl  = rb + j * 4;
    int tok = tok0 + tl;
    int dd  = d0 + c;
    float y = bf2f(tile[c][tl]);
    float uu = bf2f(ub[(size_t)tok * D_INNER + dd]);
    float z  = bf2f(xz[(size_t)tok * (2*D_INNER) + D_INNER + dd]);
    float v  = (y + uu * Dp[dd]) * (z / (1.0f + __expf(-z)));
    yg[(size_t)tok * D_INNER + dd] = f2bf(v);
  }
}

extern "C" void kernel_launch(void* const* d_in, const int* in_sizes, int n_in,
                              void* d_out, int out_size, void* d_ws, size_t ws_size,
                              hipStream_t stream) {
  (void)in_sizes; (void)n_in; (void)out_size; (void)ws_size;
  const float* x      = (const float*)d_in[0];
  const float* W_in   = (const float*)d_in[1];
  const float* W_out  = (const float*)d_in[2];
  const float* conv_w = (const float*)d_in[3];
  const float* conv_b = (const float*)d_in[4];
  const float* W_x    = (const float*)d_in[5];
  const float* W_dt   = (const float*)d_in[6];
  const float* b_dt   = (const float*)d_in[7];
  const float* A_log  = (const float*)d_in[8];
  const float* Dp     = (const float*)d_in[9];

  size_t off = 0;
  char* wsb = (char*)d_ws;
  auto alloc = [&](size_t bytes) -> void* {
    void* p = wsb + off;
    off += (bytes + 255) & ~(size_t)255;
    return p;
  };
  u16*   x_bf    = (u16*)alloc((size_t)TOKENS * D_MODEL * 2);
  u16*   Win_bf  = (u16*)alloc((size_t)2 * D_INNER * D_MODEL * 2);
  u16*   Wx_bf   = (u16*)alloc((size_t)NPROJ * D_INNER * 2);
  u16*   Wdt_bf  = (u16*)alloc((size_t)D_INNER * DT_RANK * 2);
  u16*   Wout_bf = (u16*)alloc((size_t)D_MODEL * D_INNER * 2);
  u16*   xz_bf   = (u16*)alloc((size_t)TOKENS * 2 * D_INNER * 2);
  u16*   u_bf    = (u16*)alloc((size_t)TOKENS * D_INNER * 2);
  float* xdbl    = (float*)alloc((size_t)TOKENS * NPROJ * 4);
  u16*   dtlo_bf = (u16*)alloc((size_t)TOKENS * DT_RANK * 2);
  u16*   BC_bf   = (u16*)alloc((size_t)TOKENS * 256 * 2);
  float* dt_f    = (float*)alloc((size_t)TOKENS * D_INNER * 4);
  u16*   ysT     = (u16*)alloc((size_t)D_INNER * TOKENS * 2);
  u16*   yg      = (u16*)alloc((size_t)TOKENS * D_INNER * 2);

  auto cvt = [&](const float* src, u16* dst, size_t n) {
    int n4 = (int)(n / 4);
    k_cvt_bf16<<<(n4 + 255) / 256, 256, 0, stream>>>(src, dst, n4);
  };
  cvt(x,     x_bf,    (size_t)TOKENS * D_MODEL);
  cvt(W_in,  Win_bf,  (size_t)2 * D_INNER * D_MODEL);
  cvt(W_x,   Wx_bf,   (size_t)NPROJ * D_INNER);
  cvt(W_dt,  Wdt_bf,  (size_t)D_INNER * DT_RANK);
  cvt(W_out, Wout_bf, (size_t)D_MODEL * D_INNER);

  dim3 blk(256);
  // 1) xz = x @ W_in^T  -> bf16 (TOKENS x 4096)
  k_gemm_bt<1><<<dim3(TOKENS/128, (2*D_INNER)/128), blk, 0, stream>>>(
      x_bf, Win_bf, xz_bf, nullptr, TOKENS, 2*D_INNER, D_MODEL, 2*D_INNER);
  // 2) u = silu(convs(xc))
  k_conv_silu<<<(TOKENS * D_INNER) / 256, blk, 0, stream>>>(xz_bf, conv_w, conv_b, u_bf);
  // 3) x_dbl = u @ W_x^T  (TOKENS x 320, f32)
  k_gemm_bt<0><<<dim3(TOKENS/128, (NPROJ + 127)/128), blk, 0, stream>>>(
      u_bf, Wx_bf, xdbl, nullptr, TOKENS, NPROJ, D_INNER, NPROJ);
  // 4) split into dtlo(bf16) + interleaved BC(bf16)
  k_split<<<((TOKENS * NPROJ) + 255) / 256, blk, 0, stream>>>(xdbl, dtlo_bf, BC_bf);
  // 5) dt = softplus(dtlo @ W_dt^T + 2*b_dt)  (TOKENS x 2048, f32)
  k_gemm_bt<2><<<dim3(TOKENS/128, D_INNER/128), blk, 0, stream>>>(
      dtlo_bf, Wdt_bf, dt_f, b_dt, TOKENS, D_INNER, DT_RANK, D_INNER);
  // 6) selective scan -> ysT [d][b][t] bf16
  k_scan<<<(BATCH * D_INNER) / 4, blk, 0, stream>>>(dt_f, u_bf, BC_bf, A_log, ysT);
  // 7) gate: yg = (ys + u*Dp) * silu(z) -> bf16 (TOKENS x 2048)
  k_gate<<<dim3(TOKENS/64, D_INNER/64), blk, 0, stream>>>(ysT, u_bf, xz_bf, Dp, yg);
  // 8) out = yg @ W_out^T -> f32 (TOKENS x 1024)
  k_gemm_bt<0><<<dim3(TOKENS/128, D_MODEL/128), blk, 0, stream>>>(
      yg, Wout_bf, d_out, nullptr, TOKENS, D_MODEL, D_INNER, D_MODEL);
}

// Round 3
// 537.787 us; speedup vs baseline: 1.2376x; 1.2376x over previous
//
#include <hip/hip_runtime.h>
#include <stdint.h>
#include <math.h>

#define D_MODEL 1024
#define D_STATE 128
#define D_INNER 2048
#define DT_RANK 64
#define BATCH   2
#define SEQ     2048
#define TOKENS  (BATCH*SEQ)        // 4096
#define NPROJ   (DT_RANK + 2*D_STATE) // 320

typedef unsigned short u16;
typedef __attribute__((ext_vector_type(4))) float f32x4;
typedef __attribute__((ext_vector_type(8))) short s16x8;
typedef __attribute__((ext_vector_type(4))) unsigned short u16x4;

#if __has_builtin(__builtin_amdgcn_exp2f)
#define EXP2(x) __builtin_amdgcn_exp2f(x)
#else
#define EXP2(x) __expf((x) * 0.6931471805599453f)
#endif

static __device__ __forceinline__ u16 f2bf(float f) {
  unsigned u = __builtin_bit_cast(unsigned, f);
  return (u16)((u + 0x7FFFu + ((u >> 16) & 1u)) >> 16);
}
static __device__ __forceinline__ float bf2f(u16 h) {
  return __builtin_bit_cast(float, ((unsigned)h) << 16);
}

static __device__ __forceinline__ void gload_lds16(const void* g, void* l) {
  __builtin_amdgcn_global_load_lds(
      (const __attribute__((address_space(1))) void*)g,
      (__attribute__((address_space(3))) void*)l, 16, 0, 0);
}

// ---------------- fp32 -> bf16 convert (vec4) ----------------
__global__ void k_cvt_bf16(const float* __restrict__ in, u16* __restrict__ out, int n4) {
  int i = blockIdx.x * blockDim.x + threadIdx.x;
  if (i >= n4) return;
  f32x4 v = ((const f32x4*)in)[i];
  u16x4 o;
  o.x = f2bf(v.x); o.y = f2bf(v.y); o.z = f2bf(v.z); o.w = f2bf(v.w);
  ((u16x4*)out)[i] = o;
}

// ---------------- bf16 GEMM: C = A @ B^T ----------------
// A: (M,K) bf16 row-major, B: (N,K) bf16 row-major.
// EPI: 0 = f32 store, 1 = bf16 store,
//      3 = dt path: v=softplus(acc+2*bias[col]); store float2{v, v*u[row,col]}
#define BM 128
#define BN 128
#define BK 64

template<int EPI>
__global__ __launch_bounds__(256) void k_gemm_bt(
    const u16* __restrict__ A, const u16* __restrict__ B,
    void* __restrict__ C, const float* __restrict__ bias,
    const u16* __restrict__ U,
    int M, int N, int K, int ldc)
{
  __shared__ __align__(16) u16 As[BM*BK];
  __shared__ __align__(16) u16 Bs[BN*BK];
  const int tid  = threadIdx.x;
  const int lane = tid & 63;
  const int wid  = tid >> 6;
  const int wr   = (wid >> 1) * 64;
  const int wc   = (wid & 1) * 64;
  const int bm   = blockIdx.x * BM;
  const int bn   = blockIdx.y * BN;
  const int lr   = lane & 15;        // row/col within 16x16 frag
  const int lk   = (lane >> 4) * 8;  // k offset within 32

  f32x4 acc[4][4] = {};

  for (int k0 = 0; k0 < K; k0 += BK) {
    #pragma unroll
    for (int i = 0; i < 4; ++i) {
      int c   = tid + i * 256;
      int row = c >> 3;
      int col = (c & 7) * 8;
      const u16* ga = A + (size_t)(bm + row) * K + (k0 + col);
      gload_lds16(ga, As + (size_t)c * 8);
      int brow = bn + row; brow = brow < N ? brow : N - 1; // clamp for N tail
      const u16* gb = B + (size_t)brow * K + (k0 + col);
      gload_lds16(gb, Bs + (size_t)c * 8);
    }
    __syncthreads();

    #pragma unroll
    for (int kk = 0; kk < BK; kk += 32) {
      s16x8 af[4], bf[4];
      #pragma unroll
      for (int m = 0; m < 4; ++m)
        af[m] = *(const s16x8*)(As + (size_t)(wr + m*16 + lr) * BK + kk + lk);
      #pragma unroll
      for (int n = 0; n < 4; ++n)
        bf[n] = *(const s16x8*)(Bs + (size_t)(wc + n*16 + lr) * BK + kk + lk);
      #pragma unroll
      for (int m = 0; m < 4; ++m)
        #pragma unroll
        for (int n = 0; n < 4; ++n)
          acc[m][n] = __builtin_amdgcn_mfma_f32_16x16x32_bf16(af[m], bf[n], acc[m][n], 0, 0, 0);
    }
    __syncthreads();
  }

  // epilogue: D row = (lane>>4)*4 + reg, col = lane&15  [m89-verified layout]
  const int orow0 = bm + wr + (lane >> 4) * 4;
  const int ocol0 = bn + wc + lr;
  #pragma unroll
  for (int m = 0; m < 4; ++m) {
    #pragma unroll
    for (int n = 0; n < 4; ++n) {
      int col = ocol0 + n * 16;
      if (col >= N) continue;
      #pragma unroll
      for (int r = 0; r < 4; ++r) {
        int row = orow0 + m * 16 + r;
        float v = acc[m][n][r];
        if (EPI == 3) {
          v = v + 2.0f * bias[col];
          v = (v > 20.0f) ? v : log1pf(__expf(v));
          float uu = bf2f(U[(size_t)row * D_INNER + col]);
          ((float2*)C)[(size_t)row * ldc + col] = make_float2(v, v * uu);
        } else if (EPI == 1) {
          ((u16*)C)[(size_t)row * ldc + col] = f2bf(v);
        } else {
          ((float*)C)[(size_t)row * ldc + col] = v;
        }
      }
    }
  }
}

// ---------------- depthwise causal conv (K=4) + SiLU ----------------
__global__ __launch_bounds__(256) void k_conv_silu(
    const u16* __restrict__ xz, const float* __restrict__ cw,
    const float* __restrict__ cb, u16* __restrict__ u)
{
  int idx = blockIdx.x * 256 + threadIdx.x;
  int d   = idx & (D_INNER - 1);
  int tok = idx >> 11;
  int t   = tok & (SEQ - 1);
  int b   = tok >> 11;
  f32x4 w = *(const f32x4*)(cw + (size_t)d * 4);
  float acc = cb[d];
  #pragma unroll
  for (int j = 0; j < 4; ++j) {
    int tt = t - 3 + j;
    if (tt >= 0)
      acc += bf2f(xz[(size_t)(b * SEQ + tt) * (2*D_INNER) + d]) * w[j];
  }
  float s = acc / (1.0f + __expf(-acc));
  u[(size_t)tok * D_INNER + d] = f2bf(s);
}

// ---------------- split x_dbl -> dtlo bf16, interleaved BC f32 ----------------
// BC layout per token (256 f32): lane l gets {B[2l],B[2l+1],C[2l],C[2l+1]} at 4*l
__global__ void k_split(const float* __restrict__ xdbl, u16* __restrict__ dtlo,
                        float* __restrict__ BC)
{
  int idx = blockIdx.x * 256 + threadIdx.x;
  if (idx >= TOKENS * NPROJ) return;
  int row = idx / NPROJ;
  int c   = idx - row * NPROJ;
  float v = xdbl[idx];
  if (c < DT_RANK) {
    dtlo[(size_t)row * DT_RANK + c] = f2bf(v);
  } else if (c < DT_RANK + D_STATE) {
    int n = c - DT_RANK;
    BC[(size_t)row * 256 + (n >> 1) * 4 + (n & 1)] = v;
  } else {
    int n = c - DT_RANK - D_STATE;
    BC[(size_t)row * 256 + (n >> 1) * 4 + 2 + (n & 1)] = v;
  }
}

// ---------------- selective scan: 1 wave per (b,d), 2 states/lane ----------------
// dtdu: float2 {dt, dt*u} at [b][t][d]; BC: f32 interleaved [b][t][256]
// ysT layout: [d][b][t]
#define SCHUNK 32

__global__ __launch_bounds__(256) void k_scan(
    const float2* __restrict__ dtdu, const float* __restrict__ BC,
    const float* __restrict__ A_log, u16* __restrict__ ysT)
{
  __shared__ float red[4][SCHUNK * 64];   // 8KB per wave
  const int lane = threadIdx.x & 63;
  const int wid  = threadIdx.x >> 6;
  int gw = __builtin_amdgcn_readfirstlane(blockIdx.x * 4 + wid);
  const int b = gw >> 11;
  const int d = gw & (D_INNER - 1);

  float2 al = *(const float2*)(A_log + (size_t)d * D_STATE + 2 * lane);
  const float A0 = -__expf(al.x) * 1.44269504f;   // A * log2(e)
  const float A1 = -__expf(al.y) * 1.44269504f;
  float h0 = 0.f, h1 = 0.f;

  const float2* dcol = dtdu + (size_t)b * SEQ * D_INNER + d;   // wave-uniform -> s_load
  const float*  BCb  = BC + (size_t)b * SEQ * 256 + 4 * lane;
  u16* yo = ysT + ((size_t)d * BATCH + b) * SEQ;

  float* myred = red[wid];
  // swizzled write pointers: row tt, float index (lane ^ ((tt&7)<<2))
  float* wptr[8];
  #pragma unroll
  for (int j = 0; j < 8; ++j) wptr[j] = myred + (lane ^ (j << 2));

  const int r  = lane & 31;   // output row this lane reduces
  const int hf = lane >> 5;   // which half of the row
  const float* rrow = myred + r * 64;

  for (int t0 = 0; t0 < SEQ; t0 += SCHUNK) {
    #pragma unroll
    for (int tt = 0; tt < SCHUNK; ++tt) {
      float2 sd = dcol[(size_t)(t0 + tt) * D_INNER];     // {dt, dt*u} scalar
      f32x4 bc = *(const f32x4*)(BCb + (size_t)(t0 + tt) * 256); // B0,B1,C0,C1
      float dA0 = EXP2(sd.x * A0);
      float dA1 = EXP2(sd.x * A1);
      h0 = fmaf(dA0, h0, sd.y * bc.x);
      h1 = fmaf(dA1, h1, sd.y * bc.y);
      float yp = fmaf(h1, bc.w, h0 * bc.z);
      wptr[tt & 7][tt * 64] = yp;                        // ds_write_b32
    }
    __syncthreads();   // waves in lockstep; also orders LDS write->read safely
    f32x4 s4 = {0.f, 0.f, 0.f, 0.f};
    #pragma unroll
    for (int k = 0; k < 8; ++k) {
      int off = (hf * 32 + k * 4) ^ ((r & 7) << 2);
      s4 += *(const f32x4*)(rrow + off);
    }
    float s = (s4.x + s4.y) + (s4.z + s4.w);
    float y = s + __shfl_xor(s, 32);
    if (hf == 0) yo[t0 + r] = f2bf(y);
    __syncthreads();   // protect next chunk's writes vs this chunk's reads
  }
}

// ---------------- gate: yg = (ysT^T + u*Dp) * silu(z), tiled transpose ----------------
__global__ __launch_bounds__(256) void k_gate(
    const u16* __restrict__ ysT, const u16* __restrict__ ub,
    const u16* __restrict__ xz, const float* __restrict__ Dp,
    u16* __restrict__ yg)
{
  __shared__ u16 tile[64][68];
  const int tid  = threadIdx.x;
  const int c    = tid & 63;
  const int rb   = tid >> 6;
  const int tok0 = blockIdx.x * 64;
  const int d0   = blockIdx.y * 64;
  const int bb   = tok0 >> 11;
  const int t0   = tok0 & (SEQ - 1);

  #pragma unroll
  for (int j = 0; j < 16; ++j) {
    int dl = rb + j * 4;
    tile[dl][c] = ysT[((size_t)(d0 + dl) * BATCH + bb) * SEQ + t0 + c];
  }
  __syncthreads();
  #pragma unroll
  for (int j = 0; j < 16; ++j) {
    int tl  = rb + j * 4;
    int tok = tok0 + tl;
    int dd  = d0 + c;
    float y = bf2f(tile[c][tl]);
    float uu = bf2f(ub[(size_t)tok * D_INNER + dd]);
    float z  = bf2f(xz[(size_t)tok * (2*D_INNER) + D_INNER + dd]);
    float v  = (y + uu * Dp[dd]) * (z / (1.0f + __expf(-z)));
    yg[(size_t)tok * D_INNER + dd] = f2bf(v);
  }
}

extern "C" void kernel_launch(void* const* d_in, const int* in_sizes, int n_in,
                              void* d_out, int out_size, void* d_ws, size_t ws_size,
                              hipStream_t stream) {
  (void)in_sizes; (void)n_in; (void)out_size; (void)ws_size;
  const float* x      = (const float*)d_in[0];
  const float* W_in   = (const float*)d_in[1];
  const float* W_out  = (const float*)d_in[2];
  const float* conv_w = (const float*)d_in[3];
  const float* conv_b = (const float*)d_in[4];
  const float* W_x    = (const float*)d_in[5];
  const float* W_dt   = (const float*)d_in[6];
  const float* b_dt   = (const float*)d_in[7];
  const float* A_log  = (const float*)d_in[8];
  const float* Dp     = (const float*)d_in[9];

  size_t off = 0;
  char* wsb = (char*)d_ws;
  auto alloc = [&](size_t bytes) -> void* {
    void* p = wsb + off;
    off += (bytes + 255) & ~(size_t)255;
    return p;
  };
  u16*    x_bf    = (u16*)alloc((size_t)TOKENS * D_MODEL * 2);
  u16*    Win_bf  = (u16*)alloc((size_t)2 * D_INNER * D_MODEL * 2);
  u16*    Wx_bf   = (u16*)alloc((size_t)NPROJ * D_INNER * 2);
  u16*    Wdt_bf  = (u16*)alloc((size_t)D_INNER * DT_RANK * 2);
  u16*    Wout_bf = (u16*)alloc((size_t)D_MODEL * D_INNER * 2);
  u16*    xz_bf   = (u16*)alloc((size_t)TOKENS * 2 * D_INNER * 2);
  u16*    u_bf    = (u16*)alloc((size_t)TOKENS * D_INNER * 2);
  float*  xdbl    = (float*)alloc((size_t)TOKENS * NPROJ * 4);
  u16*    dtlo_bf = (u16*)alloc((size_t)TOKENS * DT_RANK * 2);
  float*  BC_f    = (float*)alloc((size_t)TOKENS * 256 * 4);
  float2* dtdu    = (float2*)alloc((size_t)TOKENS * D_INNER * 8);
  u16*    ysT     = (u16*)alloc((size_t)D_INNER * TOKENS * 2);
  u16*    yg      = (u16*)alloc((size_t)TOKENS * D_INNER * 2);

  auto cvt = [&](const float* src, u16* dst, size_t n) {
    int n4 = (int)(n / 4);
    k_cvt_bf16<<<(n4 + 255) / 256, 256, 0, stream>>>(src, dst, n4);
  };
  cvt(x,     x_bf,    (size_t)TOKENS * D_MODEL);
  cvt(W_in,  Win_bf,  (size_t)2 * D_INNER * D_MODEL);
  cvt(W_x,   Wx_bf,   (size_t)NPROJ * D_INNER);
  cvt(W_dt,  Wdt_bf,  (size_t)D_INNER * DT_RANK);
  cvt(W_out, Wout_bf, (size_t)D_MODEL * D_INNER);

  dim3 blk(256);
  // 1) xz = x @ W_in^T  -> bf16 (TOKENS x 4096)
  k_gemm_bt<1><<<dim3(TOKENS/128, (2*D_INNER)/128), blk, 0, stream>>>(
      x_bf, Win_bf, xz_bf, nullptr, nullptr, TOKENS, 2*D_INNER, D_MODEL, 2*D_INNER);
  // 2) u = silu(conv(xc))
  k_conv_silu<<<(TOKENS * D_INNER) / 256, blk, 0, stream>>>(xz_bf, conv_w, conv_b, u_bf);
  // 3) x_dbl = u @ W_x^T  (TOKENS x 320, f32)
  k_gemm_bt<0><<<dim3(TOKENS/128, (NPROJ + 127)/128), blk, 0, stream>>>(
      u_bf, Wx_bf, xdbl, nullptr, nullptr, TOKENS, NPROJ, D_INNER, NPROJ);
  // 4) split into dtlo(bf16) + interleaved BC(f32)
  k_split<<<((TOKENS * NPROJ) + 255) / 256, blk, 0, stream>>>(xdbl, dtlo_bf, BC_f);
  // 5) dtdu = {softplus(dtlo @ W_dt^T + 2*b_dt), dt*u}  (TOKENS x 2048, float2)
  k_gemm_bt<3><<<dim3(TOKENS/128, D_INNER/128), blk, 0, stream>>>(
      dtlo_bf, Wdt_bf, dtdu, b_dt, u_bf, TOKENS, D_INNER, DT_RANK, D_INNER);
  // 6) selective scan -> ysT [d][b][t] bf16
  k_scan<<<(BATCH * D_INNER) / 4, blk, 0, stream>>>(dtdu, BC_f, A_log, ysT);
  // 7) gate: yg = (ys + u*Dp) * silu(z) -> bf16 (TOKENS x 2048)
  k_gate<<<dim3(TOKENS/64, D_INNER/64), blk, 0, stream>>>(ysT, u_bf, xz_bf, Dp, yg);
  // 8) out = yg @ W_out^T -> f32 (TOKENS x 1024)
  k_gemm_bt<0><<<dim3(TOKENS/128, D_MODEL/128), blk, 0, stream>>>(
      yg, Wout_bf, d_out, nullptr, nullptr, TOKENS, D_MODEL, D_INNER, D_MODEL);
}